// Round 10
// baseline (271.403 us; speedup 1.0000x reference)
//
#include <hip/hip_runtime.h>

// ============================================================================
// Causal MHA with RoPE. FP32 in/out; bf16 MFMA internally.
//   B=4 T=2048 D=1024 h=16 d_k=64, theta=10000
// R10 changes (flash only; rest unchanged for isolation):
//  - phase-split K-loop: QK+softmax+P for both halves, THEN one PV phase with
//    vb read once per (ks,dt) and shared by both halves (R9 read the same
//    V-frags twice per wave-iter: 16 b128 -> 8). pa[2][2] hoisted.
//  - qt pairing (g, 15-g): 512 blocks x uniform 34 iters -> every CU holds 2
//    equal blocks, steady 8 waves/CU (R9's qt-descending 1024-grid decayed to
//    ~1.5 blocks/CU from the causal tail; Occ 18.8%).
// Flash remains LDS-pipe-bound: ~1350 instr-cyc/block-iter after dedup.
// ============================================================================

typedef unsigned short u16;
typedef short short8 __attribute__((ext_vector_type(8)));
typedef float f32x4 __attribute__((ext_vector_type(4)));

#if defined(__has_builtin)
#if __has_builtin(__builtin_amdgcn_exp2f)
#define EXP2(x) __builtin_amdgcn_exp2f(x)
#else
#define EXP2(x) exp2f(x)
#endif
#else
#define EXP2(x) exp2f(x)
#endif

#define QSCALE 0.18033688011112042f     // (1/sqrt(64)) * log2(e)
#define NEG_L2T_32 -0.4152410118609203f // -log2(10000)/32

__device__ __forceinline__ float bf2f(u16 u) {
  return __uint_as_float(((unsigned int)u) << 16);
}
__device__ __forceinline__ u16 f2bf(float f) {
  unsigned int x = __float_as_uint(f);
  x += 0x7fff + ((x >> 16) & 1);  // RNE
  return (u16)(x >> 16);
}

// async 16B global -> LDS (wave-uniform LDS base + lane*16) [m97/m104]
__device__ __forceinline__ void glds16(const u16* g, u16* l) {
  __builtin_amdgcn_global_load_lds(
      (const __attribute__((address_space(1))) unsigned int*)g,
      (__attribute__((address_space(3))) unsigned int*)l, 16, 0, 0);
}

// ---------------------------------------------------------------------------
// Fused fp32->bf16 for all inputs in one launch.
// ---------------------------------------------------------------------------
__global__ __launch_bounds__(256) void cvt_all(
    const float* __restrict__ X, const float* __restrict__ Wq,
    const float* __restrict__ Wk, const float* __restrict__ Wv,
    const float* __restrict__ Wo, u16* __restrict__ Xb,
    u16* __restrict__ Wqkvb, u16* __restrict__ Wob) {
  const int gid = blockIdx.x * 256 + threadIdx.x;
  const int i = gid * 8;
  const int M1 = 1 << 20;
  const float* src;
  u16* dst;
  int off;
  if (i < 8 * M1)        { src = X;  dst = Xb;            off = 0; }
  else if (i < 9 * M1)   { src = Wq; dst = Wqkvb;         off = 8 * M1; }
  else if (i < 10 * M1)  { src = Wk; dst = Wqkvb + M1;    off = 9 * M1; }
  else if (i < 11 * M1)  { src = Wv; dst = Wqkvb + 2*M1;  off = 10 * M1; }
  else                   { src = Wo; dst = Wob;           off = 11 * M1; }
  const int j = i - off;
  const float4 a = *(const float4*)(src + j);
  const float4 b = *(const float4*)(src + j + 4);
  short8 o;
  o[0] = (short)f2bf(a.x); o[1] = (short)f2bf(a.y);
  o[2] = (short)f2bf(a.z); o[3] = (short)f2bf(a.w);
  o[4] = (short)f2bf(b.x); o[5] = (short)f2bf(b.y);
  o[6] = (short)f2bf(b.z); o[7] = (short)f2bf(b.w);
  *(short8*)(dst + j) = o;
}

// ---------------------------------------------------------------------------
// Fused QKV NT GEMM + inline-RoPE epilogue.  BK=64, XOR-swizzled LDS.
// ---------------------------------------------------------------------------
__global__ __launch_bounds__(256) void gemm_qkv(const u16* __restrict__ A,
                                                const u16* __restrict__ W,
                                                const int* __restrict__ pos,
                                                u16* __restrict__ Qr,
                                                u16* __restrict__ Kr,
                                                u16* __restrict__ Vd) {
  const int K = 1024;
  __shared__ __align__(16) u16 As[128 * 64];   // 16 KB
  __shared__ __align__(16) u16 Bs[128 * 64];   // 16 KB
  const int tid = threadIdx.x;
  const int m0 = blockIdx.y << 7;
  const int n0 = blockIdx.x << 7;
  const int w = tid >> 6, L = tid & 63;
  const int wm = (w >> 1) << 6, wn = (w & 1) << 6;
  const int lane15 = L & 15, quad = L >> 4;

  f32x4 acc[4][4] = {};

  const u16* Ap[4]; const u16* Bp[4];
  u16* Al[4]; u16* Bl[4];
#pragma unroll
  for (int i = 0; i < 4; ++i) {
    const int s = tid + (i << 8);
    const int row = s >> 3;
    const int c = ((s & 7) ^ (row & 7)) << 3;   // swizzled source chunk
    Ap[i] = A + (size_t)(m0 + row) * K + c;
    Bp[i] = W + (size_t)(n0 + row) * K + c;
    Al[i] = &As[s * 8];
    Bl[i] = &Bs[s * 8];
  }

  int offA[4][2], offB[4][2];
#pragma unroll
  for (int mt = 0; mt < 4; ++mt) {
    const int ra = wm + mt * 16 + lane15;
    const int rb = wn + mt * 16 + lane15;
    offA[mt][0] = ra * 64 + ((quad ^ (ra & 7)) << 3);
    offA[mt][1] = ra * 64 + (((quad + 4) ^ (ra & 7)) << 3);
    offB[mt][0] = rb * 64 + ((quad ^ (rb & 7)) << 3);
    offB[mt][1] = rb * 64 + (((quad + 4) ^ (rb & 7)) << 3);
  }

  for (int k0 = 0; k0 < K; k0 += 64) {
    __syncthreads();
#pragma unroll
    for (int i = 0; i < 4; ++i) glds16(Ap[i] + k0, Al[i]);
#pragma unroll
    for (int i = 0; i < 4; ++i) glds16(Bp[i] + k0, Bl[i]);
    __syncthreads();
#pragma unroll
    for (int ks = 0; ks < 2; ++ks) {
      short8 a[4], b[4];
#pragma unroll
      for (int mt = 0; mt < 4; ++mt) a[mt] = *(const short8*)&As[offA[mt][ks]];
#pragma unroll
      for (int nt = 0; nt < 4; ++nt) b[nt] = *(const short8*)&Bs[offB[nt][ks]];
#pragma unroll
      for (int mt = 0; mt < 4; ++mt)
#pragma unroll
        for (int nt = 0; nt < 4; ++nt)
          acc[mt][nt] =
              __builtin_amdgcn_mfma_f32_16x16x32_bf16(a[mt], b[nt], acc[mt][nt], 0, 0, 0);
    }
  }

  const int sel = n0 >> 10;            // 0=Q, 1=K, 2=V (uniform per block)
  const int ncol0 = (n0 & 1023) + wn;
  if (sel == 2) {
#pragma unroll
    for (int mt = 0; mt < 4; ++mt) {
      const int rbase = m0 + wm + mt * 16 + (quad << 2);
#pragma unroll
      for (int nt = 0; nt < 4; ++nt) {
        const int col = ncol0 + nt * 16 + lane15;
#pragma unroll
        for (int r = 0; r < 4; ++r)
          Vd[(size_t)(rbase + r) * 1024 + col] = f2bf(acc[mt][nt][r]);
      }
    }
  } else {
    u16* dst = sel ? Kr : Qr;
    const float sc = sel ? 1.0f : QSCALE;
    float invf[4];
#pragma unroll
    for (int nt = 0; nt < 4; ++nt) {
      const int d2 = ((ncol0 + nt * 16 + lane15) & 63) >> 1;
      invf[nt] = EXP2((float)d2 * NEG_L2T_32);
    }
#pragma unroll
    for (int mt = 0; mt < 4; ++mt) {
      const int rbase = m0 + wm + mt * 16 + (quad << 2);
#pragma unroll
      for (int r = 0; r < 4; ++r) {
        const int m = rbase + r;
        const int bb = m >> 11, tt = m & 2047;
        const float posf = (float)pos[tt];
#pragma unroll
        for (int nt = 0; nt < 4; ++nt) {
          const int col = ncol0 + nt * 16 + lane15;
          const int h = col >> 6, dcol = col & 63;
          float sn, cn;
          __sincosf(posf * invf[nt], &sn, &cn);
          const float self = acc[mt][nt][r];
          const float part = __shfl_xor(self, 1, 64);  // RoPE pair partner
          const float res = (dcol & 1) ? (part * sn + self * cn)
                                       : (self * cn - part * sn);
          dst[(((size_t)((bb * 16 + h) * 2048 + tt)) << 6) + dcol] = f2bf(res * sc);
        }
      }
    }
  }
}

// ---------------------------------------------------------------------------
// NT GEMM (out-proj): 64x128 tile -> 1024 blocks (4/CU). fp32 out.
// ---------------------------------------------------------------------------
__global__ __launch_bounds__(256) void gemm_bt(const u16* __restrict__ A,
                                               const u16* __restrict__ B,
                                               float* __restrict__ C,
                                               int M, int N, int K) {
  __shared__ __align__(16) u16 As[64 * 32];    // 4 KB
  __shared__ __align__(16) u16 Bs[128 * 32];   // 8 KB
  const int tid = threadIdx.x;
  const int m0 = blockIdx.y << 6;
  const int n0 = blockIdx.x << 7;
  const int w = tid >> 6, L = tid & 63;
  const int wm = (w >> 1) << 5, wn = (w & 1) << 6;  // wave: 32x64
  const int lane15 = L & 15, quad = L >> 4;
  const int koff = quad << 3;

  f32x4 acc[2][4] = {};

  const int s0 = tid, s1 = tid + 256;
  const u16* A0 = A + (size_t)(m0 + (s0 >> 2)) * K + ((s0 & 3) << 3);
  const u16* B0 = B + (size_t)(n0 + (s0 >> 2)) * K + ((s0 & 3) << 3);
  const u16* B1 = B + (size_t)(n0 + (s1 >> 2)) * K + ((s1 & 3) << 3);
  u16* asd0 = &As[s0 * 8];
  u16* bsd0 = &Bs[s0 * 8]; u16* bsd1 = &Bs[s1 * 8];

  for (int k0 = 0; k0 < K; k0 += 32) {
    __syncthreads();
    glds16(A0 + k0, asd0);
    glds16(B0 + k0, bsd0);
    glds16(B1 + k0, bsd1);
    __syncthreads();
    short8 a[2], b[4];
#pragma unroll
    for (int mt = 0; mt < 2; ++mt)
      a[mt] = *(const short8*)&As[(wm + mt * 16 + lane15) * 32 + koff];
#pragma unroll
    for (int nt = 0; nt < 4; ++nt)
      b[nt] = *(const short8*)&Bs[(wn + nt * 16 + lane15) * 32 + koff];
#pragma unroll
    for (int mt = 0; mt < 2; ++mt)
#pragma unroll
      for (int nt = 0; nt < 4; ++nt)
        acc[mt][nt] =
            __builtin_amdgcn_mfma_f32_16x16x32_bf16(a[mt], b[nt], acc[mt][nt], 0, 0, 0);
  }

#pragma unroll
  for (int mt = 0; mt < 2; ++mt) {
    const int rbase = m0 + wm + mt * 16 + (quad << 2);
#pragma unroll
    for (int nt = 0; nt < 4; ++nt) {
      const int col = n0 + wn + nt * 16 + lane15;
#pragma unroll
      for (int r = 0; r < 4; ++r)
        C[(size_t)(rbase + r) * N + col] = acc[mt][nt][r];
    }
  }
}

// ---------------------------------------------------------------------------
// V transpose: (b,t,h*64+d) -> (b*16+h, d, t) via LDS 64x64 tile.
// ---------------------------------------------------------------------------
__global__ __launch_bounds__(256) void transpose_v(const u16* __restrict__ Vlin,
                                                   u16* __restrict__ Vt) {
  __shared__ __align__(16) u16 tile[64][68];
  const int tid = threadIdx.x;
  const int bh = blockIdx.y, b = bh >> 4, h = bh & 15;
  const int t0 = blockIdx.x << 6;
#pragma unroll
  for (int i = 0; i < 4; ++i) {
    int s = tid + (i << 8);
    int tl = s >> 4, c4 = (s & 15) << 2;
    *(uint2*)&tile[tl][c4] =
        *(const uint2*)(Vlin + (((size_t)(b * 2048 + t0 + tl)) << 10) + (h << 6) + c4);
  }
  __syncthreads();
#pragma unroll
  for (int i = 0; i < 4; ++i) {
    int s = tid + (i << 8);
    int d = s >> 4, t4 = (s & 15) << 2;
    uint2 o;
    o.x = (unsigned)tile[t4 + 0][d] | ((unsigned)tile[t4 + 1][d] << 16);
    o.y = (unsigned)tile[t4 + 2][d] | ((unsigned)tile[t4 + 3][d] << 16);
    *(uint2*)(Vt + (((size_t)(bh * 64 + d)) << 11) + t0 + t4) = o;
  }
}

// ---------------------------------------------------------------------------
// Flash attention v6 (causal). 512 blocks: g = id>>6 (0..7), bh = id&63;
// block does qt=g then qt=15-g (uniform 34 K-iters; 2 blocks/CU steady).
// Q-tile 128: wave w owns rows [qt*128+w*32,+32) as 2 halves of 16.
// Per kt: phase1 = QK+softmax+P-store for both halves; phase2 = PV with
// vb read ONCE per (ks,dt) shared by both halves (dedup), pa[2][2] hoisted.
// Single-buffered K/V (register prefetch, 2 barriers/iter); per-(wave,half)
// P regions; K/V rows padded to 72; truncating P pack; max-free softmax.
// LDS 34816 B.
// ---------------------------------------------------------------------------
__global__ __launch_bounds__(256) void flash_attn(const u16* __restrict__ Q,
                                                  const u16* __restrict__ Kk,
                                                  const u16* __restrict__ Vt,
                                                  u16* __restrict__ O) {
  __shared__ __align__(16) u16 Ksm[64 * 72];      // [key][d] pad 72
  __shared__ __align__(16) u16 Vsm[64 * 72];      // [d][key] pad 72
  __shared__ __align__(16) u16 Psm[8][16 * 64];   // per (wave,half) P
  const int tid = threadIdx.x;
  const int w = tid >> 6, L = tid & 63;
  const int lane15 = L & 15, quad = L >> 4;
  const int g = blockIdx.x >> 6;
  const int bh = blockIdx.x & 63;
  const int b = bh >> 4, h = bh & 15;
  const int rq = lane15 >> 2;  // row-quad for P read swizzle

  const int s0 = tid, s1 = tid + 256;
  const u16* kbase = Kk + ((size_t)bh << 17);
  const u16* kp0 = kbase + s0 * 8;
  const u16* kp1 = kbase + s1 * 8;
  const u16* vbase = Vt + ((size_t)bh << 17);
  const u16* vp0 = vbase + (size_t)(s0 >> 3) * 2048 + (s0 & 7) * 8;
  const u16* vp1 = vbase + (size_t)(s1 >> 3) * 2048 + (s1 & 7) * 8;
  const int d0 = (s0 >> 3) * 72 + (s0 & 7) * 8;
  const int d1 = (s1 >> 3) * 72 + (s1 & 7) * 8;

  for (int pass = 0; pass < 2; ++pass) {
    const int qt = pass ? (15 - g) : g;
    const int nkt = 2 * qt + 2;

    // Q A-frags for this pass: A[m=lane15][k=quad*8+j]
    const size_t qrow = (size_t)bh * 2048 + qt * 128 + w * 32;
    short8 qa[2][2];
#pragma unroll
    for (int hf = 0; hf < 2; ++hf) {
      const size_t qb = (qrow + hf * 16 + lane15) << 6;
      qa[hf][0] = *(const short8*)(Q + qb + (quad << 3));
      qa[hf][1] = *(const short8*)(Q + qb + 32 + (quad << 3));
    }

    // preload tile 0; barrier first so prev pass's readers are done
    uint4 kr0 = *(const uint4*)kp0;
    uint4 kr1 = *(const uint4*)kp1;
    uint4 vr0 = *(const uint4*)vp0;
    uint4 vr1 = *(const uint4*)vp1;
    __syncthreads();
    *(uint4*)&Ksm[d0] = kr0; *(uint4*)&Ksm[d1] = kr1;
    *(uint4*)&Vsm[d0] = vr0; *(uint4*)&Vsm[d1] = vr1;
    __syncthreads();

    f32x4 o_acc[2][4] = {};
    float l_part[2][4] = {};
    const int B0w = qt * 128 + w * 32;

    for (int kt = 0; kt < nkt; ++kt) {
      if (kt + 1 < nkt) {  // register prefetch of next tile
        kr0 = *(const uint4*)(kp0 + (size_t)(kt + 1) * 4096);
        kr1 = *(const uint4*)(kp1 + (size_t)(kt + 1) * 4096);
        vr0 = *(const uint4*)(vp0 + (kt + 1) * 64);
        vr1 = *(const uint4*)(vp1 + (kt + 1) * 64);
      }

      // K B-frags (shared by both halves)
      short8 kb[4][2];
#pragma unroll
      for (int nt = 0; nt < 4; ++nt) {
        kb[nt][0] = *(const short8*)&Ksm[(nt * 16 + lane15) * 72 + (quad << 3)];
        kb[nt][1] = *(const short8*)&Ksm[(nt * 16 + lane15) * 72 + 32 + (quad << 3)];
      }

      const bool act0 = (kt * 64 <= B0w + 15);   // hf0 rows end B0w+15
      const bool act1 = (kt * 64 <= B0w + 31);   // hf1 rows end B0w+31

      // ---- phase 1: QK + softmax + P store, per half ----
#pragma unroll
      for (int hf = 0; hf < 2; ++hf) {
        const int B0 = B0w + hf * 16;
        if (kt * 64 > B0 + 15) continue;         // fully masked (uniform)
        u16* pw = Psm[w * 2 + hf];

        f32x4 sc[4];
#pragma unroll
        for (int nt = 0; nt < 4; ++nt) {
          f32x4 a = {};
          a = __builtin_amdgcn_mfma_f32_16x16x32_bf16(qa[hf][0], kb[nt][0], a, 0, 0, 0);
          a = __builtin_amdgcn_mfma_f32_16x16x32_bf16(qa[hf][1], kb[nt][1], a, 0, 0, 0);
          sc[nt] = a;
        }

        if (kt * 64 + 63 > B0) {                 // diagonal: causal mask
#pragma unroll
          for (int nt = 0; nt < 4; ++nt)
#pragma unroll
            for (int r = 0; r < 4; ++r) {
              const int row = B0 + (quad << 2) + r;
              const int key = kt * 64 + nt * 16 + lane15;
              if (key > row) sc[nt][r] = -1e30f;
            }
        }

#pragma unroll
        for (int nt = 0; nt < 4; ++nt) {
          const int colsw = ((nt ^ quad) << 4) + lane15;
#pragma unroll
          for (int r = 0; r < 4; ++r) {
            const float p = EXP2(sc[nt][r]);
            l_part[hf][r] += p;
            pw[((quad << 2) + r) * 64 + colsw] = (u16)(__float_as_uint(p) >> 16);
          }
        }
      }
      asm volatile("" ::: "memory");  // keep P reads below the stores

      // ---- phase 2: PV with shared vb ----
      short8 pa[2][2];
      if (act0) {
#pragma unroll
        for (int ks = 0; ks < 2; ++ks)
          pa[0][ks] = *(const short8*)&Psm[w * 2][lane15 * 64 +
                                               ((ks * 32 + quad * 8) ^ (rq << 4))];
      }
      if (act1) {
#pragma unroll
        for (int ks = 0; ks < 2; ++ks)
          pa[1][ks] = *(const short8*)&Psm[w * 2 + 1][lane15 * 64 +
                                               ((ks * 32 + quad * 8) ^ (rq << 4))];
      }
#pragma unroll
      for (int ks = 0; ks < 2; ++ks) {
#pragma unroll
        for (int dt = 0; dt < 4; ++dt) {
          const short8 vb =
              *(const short8*)&Vsm[(dt * 16 + lane15) * 72 + ks * 32 + quad * 8];
          if (act0)
            o_acc[0][dt] =
                __builtin_amdgcn_mfma_f32_16x16x32_bf16(pa[0][ks], vb, o_acc[0][dt], 0, 0, 0);
          if (act1)
            o_acc[1][dt] =
                __builtin_amdgcn_mfma_f32_16x16x32_bf16(pa[1][ks], vb, o_acc[1][dt], 0, 0, 0);
        }
      }

      if (kt + 1 < nkt) {  // single-buffer exchange (uniform)
        __syncthreads();
        *(uint4*)&Ksm[d0] = kr0; *(uint4*)&Ksm[d1] = kr1;
        *(uint4*)&Vsm[d0] = vr0; *(uint4*)&Vsm[d1] = vr1;
        __syncthreads();
      }
    }

    // epilogue per half: reduce l over 16 lanes, scale, store
#pragma unroll
    for (int hf = 0; hf < 2; ++hf) {
#pragma unroll
      for (int r = 0; r < 4; ++r) {
        float l = l_part[hf][r];
#pragma unroll
        for (int off = 1; off < 16; off <<= 1) l += __shfl_xor(l, off, 64);
        const float inv = 1.f / l;
        const int t = qt * 128 + w * 32 + hf * 16 + (quad << 2) + r;
        const size_t obase = (((size_t)b * 2048 + t) << 10) + (h << 6);
#pragma unroll
        for (int dt = 0; dt < 4; ++dt)
          O[obase + dt * 16 + lane15] = f2bf(o_acc[hf][dt][r] * inv);
      }
    }
  }
}

// ---------------------------------------------------------------------------
extern "C" void kernel_launch(void* const* d_in, const int* in_sizes, int n_in,
                              void* d_out, int out_size, void* d_ws, size_t ws_size,
                              hipStream_t stream) {
  const float* X  = (const float*)d_in[0];
  const int* pos  = (const int*)d_in[1];
  const float* Wq = (const float*)d_in[2];
  const float* Wk = (const float*)d_in[3];
  const float* Wv = (const float*)d_in[4];
  const float* Wo = (const float*)d_in[5];
  float* out = (float*)d_out;

  char* ws = (char*)d_ws;
  const size_t SZ = (size_t)8192 * 1024 * sizeof(u16);  // 16 MB per (B,T,D) bf16
  const size_t WSZ = (size_t)1024 * 1024 * sizeof(u16); //  2 MB per (D,D) bf16
  u16* Vlin = (u16*)(ws + 0 * SZ);
  u16* Qr   = (u16*)(ws + 1 * SZ);
  u16* Kr   = (u16*)(ws + 2 * SZ);
  u16* Vt   = (u16*)(ws + 3 * SZ);
  u16* Xb   = (u16*)(ws + 4 * SZ);
  u16* Oh   = Vlin;  // Vlin dead after transpose_v
  char* wtail = ws + 5 * SZ;
  u16* Wqkvb = (u16*)(wtail);                 // packed [Wq;Wk;Wv] 3072x1024
  u16* Wob   = (u16*)(wtail + 3 * WSZ);

  const dim3 blk(256);

  cvt_all<<<6144, blk, 0, stream>>>(X, Wq, Wk, Wv, Wo, Xb, Wqkvb, Wob);
  gemm_qkv<<<dim3(24, 64), blk, 0, stream>>>(Xb, Wqkvb, pos, Qr, Kr, Vlin);
  transpose_v<<<dim3(32, 64), blk, 0, stream>>>(Vlin, Vt);
  flash_attn<<<512, blk, 0, stream>>>(Qr, Kr, Vt, Oh);
  gemm_bt<<<dim3(8, 128), blk, 0, stream>>>(Oh, Wob, out, 8192, 1024, 1024);
}

// Round 11
// 260.097 us; speedup vs baseline: 1.0435x; 1.0435x over previous
//
#include <hip/hip_runtime.h>

// ============================================================================
// Causal MHA with RoPE. FP32 in/out; bf16 MFMA internally.
//   B=4 T=2048 D=1024 h=16 d_k=64, theta=10000
// R11 changes:
//  - flash: double-buffered K/V restored (52KB LDS; at 2 blocks/CU there is
//    107KB headroom) -> 1 barrier/iter (was 2). Work split unchanged.
//  - transpose_v FUSED into gemm_qkv V-epilogue (XOR-swizzled LDS [d][t]
//    round-trip through the staging buffer, coalesced Vt stores): kills a
//    32MB HBM round-trip + one launch.
//  - gemm_bt: BK=64 + XOR chunk swizzle (R9 pattern), 64x128 tile, grid 1024.
// ============================================================================

typedef unsigned short u16;
typedef short short8 __attribute__((ext_vector_type(8)));
typedef float f32x4 __attribute__((ext_vector_type(4)));

#if defined(__has_builtin)
#if __has_builtin(__builtin_amdgcn_exp2f)
#define EXP2(x) __builtin_amdgcn_exp2f(x)
#else
#define EXP2(x) exp2f(x)
#endif
#else
#define EXP2(x) exp2f(x)
#endif

#define QSCALE 0.18033688011112042f     // (1/sqrt(64)) * log2(e)
#define NEG_L2T_32 -0.4152410118609203f // -log2(10000)/32

__device__ __forceinline__ float bf2f(u16 u) {
  return __uint_as_float(((unsigned int)u) << 16);
}
__device__ __forceinline__ u16 f2bf(float f) {
  unsigned int x = __float_as_uint(f);
  x += 0x7fff + ((x >> 16) & 1);  // RNE
  return (u16)(x >> 16);
}
__device__ __forceinline__ unsigned int pack2(float x, float y) {
  return (unsigned int)f2bf(x) | ((unsigned int)f2bf(y) << 16);
}

// async 16B global -> LDS (wave-uniform LDS base + lane*16) [m97/m104]
__device__ __forceinline__ void glds16(const u16* g, u16* l) {
  __builtin_amdgcn_global_load_lds(
      (const __attribute__((address_space(1))) unsigned int*)g,
      (__attribute__((address_space(3))) unsigned int*)l, 16, 0, 0);
}

// ---------------------------------------------------------------------------
// Fused fp32->bf16 for all inputs in one launch.
// ---------------------------------------------------------------------------
__global__ __launch_bounds__(256) void cvt_all(
    const float* __restrict__ X, const float* __restrict__ Wq,
    const float* __restrict__ Wk, const float* __restrict__ Wv,
    const float* __restrict__ Wo, u16* __restrict__ Xb,
    u16* __restrict__ Wqkvb, u16* __restrict__ Wob) {
  const int gid = blockIdx.x * 256 + threadIdx.x;
  const int i = gid * 8;
  const int M1 = 1 << 20;
  const float* src;
  u16* dst;
  int off;
  if (i < 8 * M1)        { src = X;  dst = Xb;            off = 0; }
  else if (i < 9 * M1)   { src = Wq; dst = Wqkvb;         off = 8 * M1; }
  else if (i < 10 * M1)  { src = Wk; dst = Wqkvb + M1;    off = 9 * M1; }
  else if (i < 11 * M1)  { src = Wv; dst = Wqkvb + 2*M1;  off = 10 * M1; }
  else                   { src = Wo; dst = Wob;           off = 11 * M1; }
  const int j = i - off;
  const float4 a = *(const float4*)(src + j);
  const float4 b = *(const float4*)(src + j + 4);
  short8 o;
  o[0] = (short)f2bf(a.x); o[1] = (short)f2bf(a.y);
  o[2] = (short)f2bf(a.z); o[3] = (short)f2bf(a.w);
  o[4] = (short)f2bf(b.x); o[5] = (short)f2bf(b.y);
  o[6] = (short)f2bf(b.z); o[7] = (short)f2bf(b.w);
  *(short8*)(dst + j) = o;
}

// ---------------------------------------------------------------------------
// Fused QKV NT GEMM + RoPE (Q/K) + V transpose.  BK=64, XOR-swizzled LDS.
// W = packed [Wq;Wk;Wv] (3072x1024). Grid (24,64).
// Q/K tiles: inline RoPE (sincos from pos), written (b*16+h, t, 64).
// V tiles: transposed through the 32KB staging LDS (swizzled [d'][t']) and
// stored coalesced to Vt (b*16+h, d, t).
// ---------------------------------------------------------------------------
__global__ __launch_bounds__(256) void gemm_qkv(const u16* __restrict__ A,
                                                const u16* __restrict__ W,
                                                const int* __restrict__ pos,
                                                u16* __restrict__ Qr,
                                                u16* __restrict__ Kr,
                                                u16* __restrict__ Vt) {
  const int K = 1024;
  __shared__ __align__(16) u16 SM[16384];      // 32 KB: staging + V-transpose
  u16* As = SM;                                 // [128][64]
  u16* Bs = SM + 8192;                          // [128][64]
  const int tid = threadIdx.x;
  const int m0 = blockIdx.y << 7;
  const int n0 = blockIdx.x << 7;
  const int w = tid >> 6, L = tid & 63;
  const int wm = (w >> 1) << 6, wn = (w & 1) << 6;
  const int lane15 = L & 15, quad = L >> 4;

  f32x4 acc[4][4] = {};

  const u16* Ap[4]; const u16* Bp[4];
  u16* Al[4]; u16* Bl[4];
#pragma unroll
  for (int i = 0; i < 4; ++i) {
    const int s = tid + (i << 8);
    const int row = s >> 3;
    const int c = ((s & 7) ^ (row & 7)) << 3;   // swizzled source chunk
    Ap[i] = A + (size_t)(m0 + row) * K + c;
    Bp[i] = W + (size_t)(n0 + row) * K + c;
    Al[i] = &As[s * 8];
    Bl[i] = &Bs[s * 8];
  }

  int offA[4][2], offB[4][2];
#pragma unroll
  for (int mt = 0; mt < 4; ++mt) {
    const int ra = wm + mt * 16 + lane15;
    const int rb = wn + mt * 16 + lane15;
    offA[mt][0] = ra * 64 + ((quad ^ (ra & 7)) << 3);
    offA[mt][1] = ra * 64 + (((quad + 4) ^ (ra & 7)) << 3);
    offB[mt][0] = rb * 64 + ((quad ^ (rb & 7)) << 3);
    offB[mt][1] = rb * 64 + (((quad + 4) ^ (rb & 7)) << 3);
  }

  for (int k0 = 0; k0 < K; k0 += 64) {
    __syncthreads();
#pragma unroll
    for (int i = 0; i < 4; ++i) glds16(Ap[i] + k0, Al[i]);
#pragma unroll
    for (int i = 0; i < 4; ++i) glds16(Bp[i] + k0, Bl[i]);
    __syncthreads();
#pragma unroll
    for (int ks = 0; ks < 2; ++ks) {
      short8 a[4], b[4];
#pragma unroll
      for (int mt = 0; mt < 4; ++mt) a[mt] = *(const short8*)&As[offA[mt][ks]];
#pragma unroll
      for (int nt = 0; nt < 4; ++nt) b[nt] = *(const short8*)&Bs[offB[nt][ks]];
#pragma unroll
      for (int mt = 0; mt < 4; ++mt)
#pragma unroll
        for (int nt = 0; nt < 4; ++nt)
          acc[mt][nt] =
              __builtin_amdgcn_mfma_f32_16x16x32_bf16(a[mt], b[nt], acc[mt][nt], 0, 0, 0);
    }
  }

  const int sel = n0 >> 10;            // 0=Q, 1=K, 2=V (uniform per block)
  const int ncol0w = (n0 & 1023) + wn;
  if (sel == 2) {
    // ---- V: transpose via swizzled LDS [d'][t'], then coalesced Vt stores.
    // swizzle: elem(d', t) = d'*128 + ((t & ~7) ^ ((d'&15)<<3)) + (t & 7)
    const int b = m0 >> 11, t0 = m0 & 2047;
    const int h0 = (n0 & 1023) >> 6;
    __syncthreads();  // done reading staging
#pragma unroll
    for (int mt = 0; mt < 4; ++mt) {
      const int tb = wm + mt * 16 + (quad << 2);  // t' base (4-aligned)
#pragma unroll
      for (int nt = 0; nt < 4; ++nt) {
        const int dp = wn + nt * 16 + lane15;     // d' 0..127
        const int e = dp * 128 + ((tb & ~7) ^ ((dp & 15) << 3)) + (tb & 7);
        uint2 v;
        v.x = pack2(acc[mt][nt][0], acc[mt][nt][1]);
        v.y = pack2(acc[mt][nt][2], acc[mt][nt][3]);
        *(uint2*)&SM[e] = v;
      }
    }
    __syncthreads();
    const int chunk = tid & 15;       // t-chunk of 8
#pragma unroll
    for (int i = 0; i < 8; ++i) {
      const int dp = (tid >> 4) + (i << 4);       // d' 0..127
      const int e = dp * 128 + ((chunk << 3) ^ ((dp & 15) << 3));
      const uint4 v = *(const uint4*)&SM[e];
      const int bh = b * 16 + h0 + (dp >> 6);
      const int d = dp & 63;
      *(uint4*)(Vt + (((size_t)(bh * 64 + d)) << 11) + t0 + (chunk << 3)) = v;
    }
  } else {
    u16* dst = sel ? Kr : Qr;
    const float sc = sel ? 1.0f : QSCALE;
    float invf[4];
#pragma unroll
    for (int nt = 0; nt < 4; ++nt) {
      const int d2 = ((ncol0w + nt * 16 + lane15) & 63) >> 1;
      invf[nt] = EXP2((float)d2 * NEG_L2T_32);
    }
#pragma unroll
    for (int mt = 0; mt < 4; ++mt) {
      const int rbase = m0 + wm + mt * 16 + (quad << 2);
#pragma unroll
      for (int r = 0; r < 4; ++r) {
        const int m = rbase + r;
        const int bb = m >> 11, tt = m & 2047;
        const float posf = (float)pos[tt];
#pragma unroll
        for (int nt = 0; nt < 4; ++nt) {
          const int col = ncol0w + nt * 16 + lane15;
          const int h = col >> 6, dcol = col & 63;
          float sn, cn;
          __sincosf(posf * invf[nt], &sn, &cn);
          const float self = acc[mt][nt][r];
          const float part = __shfl_xor(self, 1, 64);  // RoPE pair partner
          const float res = (dcol & 1) ? (part * sn + self * cn)
                                       : (self * cn - part * sn);
          dst[(((size_t)((bb * 16 + h) * 2048 + tt)) << 6) + dcol] = f2bf(res * sc);
        }
      }
    }
  }
}

// ---------------------------------------------------------------------------
// NT GEMM (out-proj): 64x128 tile, BK=64 + XOR swizzle, grid (8,128) = 4/CU.
// fp32 out. LDS 24 KB.
// ---------------------------------------------------------------------------
__global__ __launch_bounds__(256) void gemm_bt(const u16* __restrict__ A,
                                               const u16* __restrict__ B,
                                               float* __restrict__ C,
                                               int M, int N, int K) {
  __shared__ __align__(16) u16 As[64 * 64];    //  8 KB
  __shared__ __align__(16) u16 Bs[128 * 64];   // 16 KB
  const int tid = threadIdx.x;
  const int m0 = blockIdx.y << 6;
  const int n0 = blockIdx.x << 7;
  const int w = tid >> 6, L = tid & 63;
  const int wm = (w >> 1) << 5, wn = (w & 1) << 6;  // wave: 32x64
  const int lane15 = L & 15, quad = L >> 4;

  f32x4 acc[2][4] = {};

  const u16* Ap[2]; const u16* Bp[4];
  u16* Al[2]; u16* Bl[4];
#pragma unroll
  for (int i = 0; i < 2; ++i) {
    const int s = tid + (i << 8);
    const int row = s >> 3;
    const int c = ((s & 7) ^ (row & 7)) << 3;
    Ap[i] = A + (size_t)(m0 + row) * K + c;
    Al[i] = &As[s * 8];
  }
#pragma unroll
  for (int i = 0; i < 4; ++i) {
    const int s = tid + (i << 8);
    const int row = s >> 3;
    const int c = ((s & 7) ^ (row & 7)) << 3;
    Bp[i] = B + (size_t)(n0 + row) * K + c;
    Bl[i] = &Bs[s * 8];
  }

  int offA[2][2], offB[4][2];
#pragma unroll
  for (int mt = 0; mt < 2; ++mt) {
    const int ra = wm + mt * 16 + lane15;
    offA[mt][0] = ra * 64 + ((quad ^ (ra & 7)) << 3);
    offA[mt][1] = ra * 64 + (((quad + 4) ^ (ra & 7)) << 3);
  }
#pragma unroll
  for (int nt = 0; nt < 4; ++nt) {
    const int rb = wn + nt * 16 + lane15;
    offB[nt][0] = rb * 64 + ((quad ^ (rb & 7)) << 3);
    offB[nt][1] = rb * 64 + (((quad + 4) ^ (rb & 7)) << 3);
  }

  for (int k0 = 0; k0 < K; k0 += 64) {
    __syncthreads();
#pragma unroll
    for (int i = 0; i < 2; ++i) glds16(Ap[i] + k0, Al[i]);
#pragma unroll
    for (int i = 0; i < 4; ++i) glds16(Bp[i] + k0, Bl[i]);
    __syncthreads();
#pragma unroll
    for (int ks = 0; ks < 2; ++ks) {
      short8 a[2], b[4];
#pragma unroll
      for (int mt = 0; mt < 2; ++mt) a[mt] = *(const short8*)&As[offA[mt][ks]];
#pragma unroll
      for (int nt = 0; nt < 4; ++nt) b[nt] = *(const short8*)&Bs[offB[nt][ks]];
#pragma unroll
      for (int mt = 0; mt < 2; ++mt)
#pragma unroll
        for (int nt = 0; nt < 4; ++nt)
          acc[mt][nt] =
              __builtin_amdgcn_mfma_f32_16x16x32_bf16(a[mt], b[nt], acc[mt][nt], 0, 0, 0);
    }
  }

#pragma unroll
  for (int mt = 0; mt < 2; ++mt) {
    const int rbase = m0 + wm + mt * 16 + (quad << 2);
#pragma unroll
    for (int nt = 0; nt < 4; ++nt) {
      const int col = n0 + wn + nt * 16 + lane15;
#pragma unroll
      for (int r = 0; r < 4; ++r)
        C[(size_t)(rbase + r) * N + col] = acc[mt][nt][r];
    }
  }
}

// ---------------------------------------------------------------------------
// Flash attention v7 (causal). 512 blocks: g = id>>6 (0..7), bh = id&63;
// block does qt=g then qt=15-g (uniform 34 K-iters; 2 blocks/CU steady).
// DOUBLE-buffered K/V (register prefetch -> LDS ping-pong, 1 barrier/iter).
// Phase-split QK/softmax then shared-vb PV. Per-(wave,half) P regions;
// K/V rows padded to 72; truncating P pack; max-free softmax. LDS 52 KB.
// nkt is always even -> buffer 0 is always free at pass start.
// ---------------------------------------------------------------------------
__global__ __launch_bounds__(256) void flash_attn(const u16* __restrict__ Q,
                                                  const u16* __restrict__ Kk,
                                                  const u16* __restrict__ Vt,
                                                  u16* __restrict__ O) {
  __shared__ __align__(16) u16 Ksm[2][64 * 72];   // [key][d] pad 72
  __shared__ __align__(16) u16 Vsm[2][64 * 72];   // [d][key] pad 72
  __shared__ __align__(16) u16 Psm[8][16 * 64];   // per (wave,half) P
  const int tid = threadIdx.x;
  const int w = tid >> 6, L = tid & 63;
  const int lane15 = L & 15, quad = L >> 4;
  const int g = blockIdx.x >> 6;
  const int bh = blockIdx.x & 63;
  const int b = bh >> 4, h = bh & 15;
  const int rq = lane15 >> 2;  // row-quad for P read swizzle

  const int s0 = tid, s1 = tid + 256;
  const u16* kbase = Kk + ((size_t)bh << 17);
  const u16* kp0 = kbase + s0 * 8;
  const u16* kp1 = kbase + s1 * 8;
  const u16* vbase = Vt + ((size_t)bh << 17);
  const u16* vp0 = vbase + (size_t)(s0 >> 3) * 2048 + (s0 & 7) * 8;
  const u16* vp1 = vbase + (size_t)(s1 >> 3) * 2048 + (s1 & 7) * 8;
  const int d0 = (s0 >> 3) * 72 + (s0 & 7) * 8;
  const int d1 = (s1 >> 3) * 72 + (s1 & 7) * 8;

  for (int pass = 0; pass < 2; ++pass) {
    const int qt = pass ? (15 - g) : g;
    const int nkt = 2 * qt + 2;

    const size_t qrow = (size_t)bh * 2048 + qt * 128 + w * 32;
    short8 qa[2][2];
#pragma unroll
    for (int hf = 0; hf < 2; ++hf) {
      const size_t qb = (qrow + hf * 16 + lane15) << 6;
      qa[hf][0] = *(const short8*)(Q + qb + (quad << 3));
      qa[hf][1] = *(const short8*)(Q + qb + 32 + (quad << 3));
    }

    // preload tile 0 into buffer 0 (always free: prev pass ended on buf 1)
    uint4 kr0 = *(const uint4*)kp0;
    uint4 kr1 = *(const uint4*)kp1;
    uint4 vr0 = *(const uint4*)vp0;
    uint4 vr1 = *(const uint4*)vp1;
    *(uint4*)&Ksm[0][d0] = kr0; *(uint4*)&Ksm[0][d1] = kr1;
    *(uint4*)&Vsm[0][d0] = vr0; *(uint4*)&Vsm[0][d1] = vr1;
    __syncthreads();

    f32x4 o_acc[2][4] = {};
    float l_part[2][4] = {};
    const int B0w = qt * 128 + w * 32;

    for (int kt = 0; kt < nkt; ++kt) {
      const int cur = kt & 1, nxt = cur ^ 1;
      if (kt + 1 < nkt) {  // register prefetch of next tile
        kr0 = *(const uint4*)(kp0 + (size_t)(kt + 1) * 4096);
        kr1 = *(const uint4*)(kp1 + (size_t)(kt + 1) * 4096);
        vr0 = *(const uint4*)(vp0 + (kt + 1) * 64);
        vr1 = *(const uint4*)(vp1 + (kt + 1) * 64);
      }
      const u16* Ks = Ksm[cur];
      const u16* Vs = Vsm[cur];

      short8 kb[4][2];
#pragma unroll
      for (int nt = 0; nt < 4; ++nt) {
        kb[nt][0] = *(const short8*)&Ks[(nt * 16 + lane15) * 72 + (quad << 3)];
        kb[nt][1] = *(const short8*)&Ks[(nt * 16 + lane15) * 72 + 32 + (quad << 3)];
      }

      const bool act0 = (kt * 64 <= B0w + 15);
      const bool act1 = (kt * 64 <= B0w + 31);

      // ---- phase 1: QK + softmax + P store, per half ----
#pragma unroll
      for (int hf = 0; hf < 2; ++hf) {
        const int B0 = B0w + hf * 16;
        if (kt * 64 > B0 + 15) continue;         // fully masked (uniform)
        u16* pw = Psm[w * 2 + hf];

        f32x4 sc[4];
#pragma unroll
        for (int nt = 0; nt < 4; ++nt) {
          f32x4 a = {};
          a = __builtin_amdgcn_mfma_f32_16x16x32_bf16(qa[hf][0], kb[nt][0], a, 0, 0, 0);
          a = __builtin_amdgcn_mfma_f32_16x16x32_bf16(qa[hf][1], kb[nt][1], a, 0, 0, 0);
          sc[nt] = a;
        }

        if (kt * 64 + 63 > B0) {                 // diagonal: causal mask
#pragma unroll
          for (int nt = 0; nt < 4; ++nt)
#pragma unroll
            for (int r = 0; r < 4; ++r) {
              const int row = B0 + (quad << 2) + r;
              const int key = kt * 64 + nt * 16 + lane15;
              if (key > row) sc[nt][r] = -1e30f;
            }
        }

#pragma unroll
        for (int nt = 0; nt < 4; ++nt) {
          const int colsw = ((nt ^ quad) << 4) + lane15;
#pragma unroll
          for (int r = 0; r < 4; ++r) {
            const float p = EXP2(sc[nt][r]);
            l_part[hf][r] += p;
            pw[((quad << 2) + r) * 64 + colsw] = (u16)(__float_as_uint(p) >> 16);
          }
        }
      }
      asm volatile("" ::: "memory");  // keep P reads below the stores

      // ---- phase 2: PV with shared vb ----
      short8 pa[2][2];
      if (act0) {
#pragma unroll
        for (int ks = 0; ks < 2; ++ks)
          pa[0][ks] = *(const short8*)&Psm[w * 2][lane15 * 64 +
                                               ((ks * 32 + quad * 8) ^ (rq << 4))];
      }
      if (act1) {
#pragma unroll
        for (int ks = 0; ks < 2; ++ks)
          pa[1][ks] = *(const short8*)&Psm[w * 2 + 1][lane15 * 64 +
                                               ((ks * 32 + quad * 8) ^ (rq << 4))];
      }
#pragma unroll
      for (int ks = 0; ks < 2; ++ks) {
#pragma unroll
        for (int dt = 0; dt < 4; ++dt) {
          const short8 vb =
              *(const short8*)&Vs[(dt * 16 + lane15) * 72 + ks * 32 + quad * 8];
          if (act0)
            o_acc[0][dt] =
                __builtin_amdgcn_mfma_f32_16x16x32_bf16(pa[0][ks], vb, o_acc[0][dt], 0, 0, 0);
          if (act1)
            o_acc[1][dt] =
                __builtin_amdgcn_mfma_f32_16x16x32_bf16(pa[1][ks], vb, o_acc[1][dt], 0, 0, 0);
        }
      }

      if (kt + 1 < nkt) {  // commit prefetched tile to the other buffer
        *(uint4*)&Ksm[nxt][d0] = kr0; *(uint4*)&Ksm[nxt][d1] = kr1;
        *(uint4*)&Vsm[nxt][d0] = vr0; *(uint4*)&Vsm[nxt][d1] = vr1;
        __syncthreads();   // single barrier per iter
      }
    }

    // epilogue per half: reduce l over 16 lanes, scale, store
#pragma unroll
    for (int hf = 0; hf < 2; ++hf) {
#pragma unroll
      for (int r = 0; r < 4; ++r) {
        float l = l_part[hf][r];
#pragma unroll
        for (int off = 1; off < 16; off <<= 1) l += __shfl_xor(l, off, 64);
        const float inv = 1.f / l;
        const int t = qt * 128 + w * 32 + hf * 16 + (quad << 2) + r;
        const size_t obase = (((size_t)b * 2048 + t) << 10) + (h << 6);
#pragma unroll
        for (int dt = 0; dt < 4; ++dt)
          O[obase + dt * 16 + lane15] = f2bf(o_acc[hf][dt][r] * inv);
      }
    }
  }
}

// ---------------------------------------------------------------------------
extern "C" void kernel_launch(void* const* d_in, const int* in_sizes, int n_in,
                              void* d_out, int out_size, void* d_ws, size_t ws_size,
                              hipStream_t stream) {
  const float* X  = (const float*)d_in[0];
  const int* pos  = (const int*)d_in[1];
  const float* Wq = (const float*)d_in[2];
  const float* Wk = (const float*)d_in[3];
  const float* Wv = (const float*)d_in[4];
  const float* Wo = (const float*)d_in[5];
  float* out = (float*)d_out;

  char* ws = (char*)d_ws;
  const size_t SZ = (size_t)8192 * 1024 * sizeof(u16);  // 16 MB per (B,T,D) bf16
  const size_t WSZ = (size_t)1024 * 1024 * sizeof(u16); //  2 MB per (D,D) bf16
  u16* Vt   = (u16*)(ws + 0 * SZ);
  u16* Qr   = (u16*)(ws + 1 * SZ);
  u16* Kr   = (u16*)(ws + 2 * SZ);
  u16* Xb   = (u16*)(ws + 3 * SZ);
  u16* Oh   = (u16*)(ws + 4 * SZ);
  char* wtail = ws + 5 * SZ;
  u16* Wqkvb = (u16*)(wtail);                 // packed [Wq;Wk;Wv] 3072x1024
  u16* Wob   = (u16*)(wtail + 3 * WSZ);

  const dim3 blk(256);

  cvt_all<<<6144, blk, 0, stream>>>(X, Wq, Wk, Wv, Wo, Xb, Wqkvb, Wob);
  gemm_qkv<<<dim3(24, 64), blk, 0, stream>>>(Xb, Wqkvb, pos, Qr, Kr, Vt);
  flash_attn<<<512, blk, 0, stream>>>(Qr, Kr, Vt, Oh);
  gemm_bt<<<dim3(8, 128), blk, 0, stream>>>(Oh, Wob, out, 8192, 1024, 1024);
}